// Round 7
// baseline (3664.882 us; speedup 1.0000x reference)
//
#include <hip/hip_runtime.h>

#define BROWS 16384
#define HDIM  4096
#define H2    2048
#define EEXP  64
#define KSEL  12

typedef float f32x4 __attribute__((ext_vector_type(4)));

typedef __attribute__((address_space(1))) const unsigned int guint_t;
typedef __attribute__((address_space(3))) unsigned int luint_t;

__device__ __forceinline__ void gl16(const void* g, void* l){
  __builtin_amdgcn_global_load_lds((guint_t*)g, (luint_t*)l, 16, 0, 0);
}

// ---------- masked_w f32, replicating np: rw * (1/(1+exp(-m))) ----------
__global__ void k_mw32(const float* __restrict__ rw, const float* __restrict__ mk,
                       float* __restrict__ mw, int n){
  int i = blockIdx.x*blockDim.x + threadIdx.x;
  if (i < n){
    float m = mk[i];
    float u = (float)exp(-(double)m);
    mw[i] = rw[i] * (1.0f/(1.0f + u));
  }
}

// ---------- generic 32x32 tiled transpose: out[C][R] = in[R][C]^T ----------
__global__ __launch_bounds__(256)
void k_tr(const float* __restrict__ in, float* __restrict__ out, int R, int C){
  __shared__ float tile[32][33];
  const int t = threadIdx.x;
  const int cb = C >> 5;
  const int bx = blockIdx.x % cb, by = blockIdx.x / cb;
  const int lr = t >> 3, lc4 = (t & 7) * 4;
  f32x4 v = *(const f32x4*)(in + (size_t)(by*32 + lr)*C + bx*32 + lc4);
  tile[lr][lc4] = v[0]; tile[lr][lc4+1] = v[1];
  tile[lr][lc4+2] = v[2]; tile[lr][lc4+3] = v[3];
  __syncthreads();
  f32x4 o;
  o[0] = tile[lc4][lr]; o[1] = tile[lc4+1][lr];
  o[2] = tile[lc4+2][lr]; o[3] = tile[lc4+3][lr];
  *(f32x4*)(out + (size_t)(bx*32 + lr)*R + by*32 + lc4) = o;
}

// ---------- big h-GEMM: h[16384 x 2048] = relu(A . B^T + b1) ----------
// 256x128 tile, 256 thr, 16x8/thread (2.67 flop/LDS-byte), A reg-staged
// (4 rows x 8 k -> 8 ds_write_b128), B via global_load_lds from Btr.
// Bit-exact np-f32 chain: ONE f32 acc per output, fmaf over k ascending.
__global__ __launch_bounds__(256, 2)
void k_h(const float* __restrict__ A, const float* __restrict__ Btr,
         const float* __restrict__ bias, float* __restrict__ C)
{
  __shared__ float As[32][256];   // k-major, 32 KB
  __shared__ float Bs[33][128];   // k-major, unpadded rows (gl_lds), 16.9 KB
  const int t = threadIdx.x, w = t>>6, l = t&63;
  const int ly = l>>3, lx = l&7;
  // XCD-chunked swizzle: 1024 wgs, xcd = bid&7 -> contiguous (mt,nt) chunk
  const int bid = blockIdx.x;
  const int q = bid >> 3;
  const int mt = (bid & 7)*8 + (q >> 4), nt = q & 15;
  const long m0 = (long)mt*256; const int n0 = nt*128;
  const int r0 = (w>>1)*64 + ly*8;          // A row base (+0..7, +128..135)
  const int c0 = (w&1)*64 + lx*8;           // B col base (+0..7)

  float acc[16][8] = {};

  // A staging: thread handles rows rg*4..+3, k-chunk kc..kc+7
  const int rg = t>>2, kc = (t&3)*8;
  const float* ag = A + (m0 + rg*4)*(size_t)HDIM + kc;
  f32x4 ar[4][2];
  auto loadA = [&](int kb){
    #pragma unroll
    for (int r=0;r<4;r++){
      ar[r][0] = *(const f32x4*)(ag + (size_t)r*HDIM + kb);
      ar[r][1] = *(const f32x4*)(ag + (size_t)r*HDIM + kb + 4);
    }
  };
  auto storeA = [&](){
    #pragma unroll
    for (int u=0;u<2;u++)
      #pragma unroll
      for (int v=0;v<4;v++){
        f32x4 w4;
        w4[0]=ar[0][u][v]; w4[1]=ar[1][u][v]; w4[2]=ar[2][u][v]; w4[3]=ar[3][u][v];
        *(f32x4*)&As[kc + u*4 + v][rg*4] = w4;
      }
  };
  // B staging: per wave 4 gl_lds, each covers 2 k-rows (1024B)
  const float* bg = Btr + n0 + (size_t)(l&31)*4 + (size_t)(l>>5)*H2;

  auto LDK = [&](int K, f32x4&A0, f32x4&A1, f32x4&A2, f32x4&A3, f32x4&B0, f32x4&B1){
    A0 = *(const f32x4*)&As[K][r0];     A1 = *(const f32x4*)&As[K][r0+4];
    A2 = *(const f32x4*)&As[K][r0+128]; A3 = *(const f32x4*)&As[K][r0+132];
    B0 = *(const f32x4*)&Bs[K][c0];     B1 = *(const f32x4*)&Bs[K][c0+4];
  };
  auto FMK = [&](const f32x4&A0, const f32x4&A1, const f32x4&A2, const f32x4&A3,
                 const f32x4&B0, const f32x4&B1){
    #pragma unroll
    for (int i=0;i<4;i++)
      #pragma unroll
      for (int j=0;j<4;j++){
        acc[i][j]      = fmaf(A0[i], B0[j], acc[i][j]);
        acc[i][j+4]    = fmaf(A0[i], B1[j], acc[i][j+4]);
        acc[i+4][j]    = fmaf(A1[i], B0[j], acc[i+4][j]);
        acc[i+4][j+4]  = fmaf(A1[i], B1[j], acc[i+4][j+4]);
        acc[i+8][j]    = fmaf(A2[i], B0[j], acc[i+8][j]);
        acc[i+8][j+4]  = fmaf(A2[i], B1[j], acc[i+8][j+4]);
        acc[i+12][j]   = fmaf(A3[i], B0[j], acc[i+12][j]);
        acc[i+12][j+4] = fmaf(A3[i], B1[j], acc[i+12][j+4]);
      }
  };

  for (int p = 0; p < 128; ++p){
    loadA(p*32);                        // issue early; in flight across barrier
    __syncthreads();                    // prior panel's LDS reads complete
    {
      const size_t kro = (size_t)(p*32 + w*8)*H2;
      #pragma unroll
      for (int i=0;i<4;i++)
        gl16(bg + kro + (size_t)(2*i)*H2, &Bs[w*8 + 2*i][0]);
    }
    storeA();                           // 8 x ds_write_b128 (waits A loads)
    asm volatile("s_waitcnt vmcnt(0)" ::: "memory");   // B DMA complete
    __syncthreads();

    f32x4 xa0,xa1,xa2,xa3,xb0,xb1, ya0,ya1,ya2,ya3,yb0,yb1;
    LDK(0, xa0,xa1,xa2,xa3,xb0,xb1);
    #pragma unroll 2
    for (int kk = 0; kk < 32; kk += 2){
      LDK(kk+1, ya0,ya1,ya2,ya3,yb0,yb1);
      FMK(xa0,xa1,xa2,xa3,xb0,xb1);
      LDK(kk+2, xa0,xa1,xa2,xa3,xb0,xb1);   // kk=30: reads spill into Bs pad (unused)
      FMK(ya0,ya1,ya2,ya3,yb0,yb1);
    }
  }

  const float* bp = bias + n0 + c0;
  f32x4 bv0 = *(const f32x4*)bp, bv1 = *(const f32x4*)(bp+4);
  #pragma unroll
  for (int i=0;i<16;i++){
    const long row = m0 + r0 + ((i<8) ? i : (128 + i - 8));
    f32x4 v0, v1;
    #pragma unroll
    for (int j=0;j<4;j++){
      v0[j] = fmaxf(acc[i][j]   + bv0[j], 0.f);
      v1[j] = fmaxf(acc[i][j+4] + bv1[j], 0.f);
    }
    *(f32x4*)&C[row*(long)H2 + n0 + c0]     = v0;
    *(f32x4*)&C[row*(long)H2 + n0 + c0 + 4] = v1;
  }
}

// ---------- small GEMM (rl, z): C = A . B^T, same bit-exact chain ----------
__global__ __launch_bounds__(256, 2)
void k_g32(const float* __restrict__ A, const float* __restrict__ B,
           float* __restrict__ C, int K, int ntiles,
           const float* __restrict__ bias, int relu)
{
  __shared__ float As[64][36];
  __shared__ float Bs[64][36];
  const int t = threadIdx.x;
  const int mt = blockIdx.x / ntiles, nt = blockIdx.x % ntiles;
  const long m0 = (long)mt*64; const int n0 = nt*64;
  const int ty = t>>4, tx = t&15;
  const int sr = t>>2, sc = (t&3)*8;
  float acc[4][4] = {{0.f,0.f,0.f,0.f},{0.f,0.f,0.f,0.f},
                     {0.f,0.f,0.f,0.f},{0.f,0.f,0.f,0.f}};
  const float* ap = A + (m0+sr)*(long)K + sc;
  const float* bp = B + ((size_t)(n0+sr))*K + sc;
  f32x4 a0,a1,b0,b1;
  auto gload = [&](int kb){
    a0 = *(const f32x4*)(ap + kb);
    a1 = *(const f32x4*)(ap + kb + 4);
    b0 = *(const f32x4*)(bp + kb);
    b1 = *(const f32x4*)(bp + kb + 4);
  };
  gload(0);
  for (int kb = 0; kb < K; kb += 32){
    __syncthreads();
    *(f32x4*)&As[sr][sc]   = a0; *(f32x4*)&As[sr][sc+4] = a1;
    *(f32x4*)&Bs[sr][sc]   = b0; *(f32x4*)&Bs[sr][sc+4] = b1;
    __syncthreads();
    if (kb + 32 < K) gload(kb + 32);
    #pragma unroll
    for (int kk = 0; kk < 32; kk += 4){
      f32x4 av[4], bv[4];
      #pragma unroll
      for (int i=0;i<4;i++) av[i] = *(const f32x4*)&As[ty+16*i][kk];
      #pragma unroll
      for (int j=0;j<4;j++) bv[j] = *(const f32x4*)&Bs[tx+16*j][kk];
      #pragma unroll
      for (int q=0;q<4;q++)
        #pragma unroll
        for (int i=0;i<4;i++)
          #pragma unroll
          for (int j=0;j<4;j++)
            acc[i][j] = fmaf(av[i][q], bv[j][q], acc[i][j]);
    }
  }
  #pragma unroll
  for (int i=0;i<4;i++){
    const long row = m0 + ty + 16*i;
    #pragma unroll
    for (int j=0;j<4;j++){
      const int col = n0 + tx + 16*j;
      float v = acc[i][j];
      if (bias) v = v + bias[col];
      if (relu) v = fmaxf(v, 0.f);
      C[row*(long)(ntiles*64) + col] = v;
    }
  }
}

// ---------- gates sigmoid + scaled logits ----------
__global__ void k_sig(const float* __restrict__ z, const float* __restrict__ rl,
                      const float* __restrict__ b2, float* __restrict__ s,
                      float* __restrict__ out0, int n){
  int i = blockIdx.x*blockDim.x + threadIdx.x;
  if (i < n){
    int e = i & (EEXP-1);
    float zz = z[i] + b2[e];
    float u = (float)exp(-(double)zz);
    float g = 1.0f/(1.0f + u);
    float sv = rl[i] * g;
    s[i] = sv;
    out0[i] = sv;
  }
}

// ---------- top-12 (stable), weights, softmax stats ----------
__global__ __launch_bounds__(256, 2)
void k_top(const float* __restrict__ s32, float* __restrict__ out,
           float* __restrict__ loadp, float* __restrict__ entp)
{
  __shared__ float P[256][65];
  __shared__ float entbuf[256];
  const int t = threadIdx.x;
  const long row = (long)blockIdx.x*256 + t;
  const float* srow = s32 + row*EEXP;

  float vals[KSEL]; int idxs[KSEL];
  float pv = INFINITY; int pi = -1;
  for (int kk=0; kk<KSEL; ++kk){
    float bv = -INFINITY; int bi = 0;
    for (int e=0; e<EEXP; ++e){
      float v = srow[e];
      bool after = (v < pv) || ((v == pv) && (e > pi));
      if (after && (v > bv)){ bv = v; bi = e; }
    }
    vals[kk] = bv; idxs[kk] = bi; pv = bv; pi = bi;
  }
  float* oi = out + (size_t)BROWS*EEXP;
  float* ow = oi + (size_t)BROWS*KSEL;
  const long obase = row*KSEL;
  {
    float ev[KSEL]; float sw = 0.f;
    #pragma unroll
    for (int kk=0; kk<KSEL; ++kk){ ev[kk] = expf(vals[kk]-vals[0]); sw += ev[kk]; }
    float inv = 1.f/sw;
    #pragma unroll
    for (int kk=0; kk<KSEL; ++kk){ oi[obase+kk] = (float)idxs[kk]; ow[obase+kk] = ev[kk]*inv; }
  }
  {
    float mx = vals[0];
    float sum = 0.f;
    for (int e=0; e<EEXP; ++e) sum += expf(srow[e] - mx);
    float isum = 1.f/sum, ent = 0.f;
    for (int e=0; e<EEXP; ++e){
      float p2 = expf(srow[e] - mx) * isum;
      ent -= p2 * logf(p2 + 1e-8f);
      P[t][e] = p2;
    }
    entbuf[t] = ent;
  }
  __syncthreads();
  if (t < 64){
    float s = 0.f;
    for (int r2=0; r2<256; ++r2) s += P[r2][t];
    loadp[blockIdx.x*64 + t] = s;
    float es = entbuf[t] + entbuf[t+64] + entbuf[t+128] + entbuf[t+192];
    for (int o=32; o; o>>=1) es += __shfl_down(es, o);
    if (t == 0) entp[blockIdx.x] = es;
  }
}

// ---------- finalize: load variance (ddof=1) + mean entropy ----------
__global__ void k_finalize(const float* __restrict__ loadp, const float* __restrict__ entp,
                           float* __restrict__ out){
  const int e = threadIdx.x;
  float s = 0.f;
  for (int b=0; b<64; ++b) s += loadp[b*64 + e];
  float load = s * (1.f/16384.f);
  float tsum = load;
  for (int o=32; o; o>>=1) tsum += __shfl_xor(tsum, o);
  float mean = tsum * (1.f/64.f);
  float d = load - mean;
  float v = d*d;
  for (int o=32; o; o>>=1) v += __shfl_xor(v, o);
  float var = v * (1.f/63.f);
  float es = entp[e];
  for (int o=32; o; o>>=1) es += __shfl_xor(es, o);
  if (e == 0){
    size_t off = (size_t)BROWS*EEXP + (size_t)BROWS*KSEL*2;
    out[off]     = var;
    out[off + 1] = es * (1.f/16384.f);
  }
}

extern "C" void kernel_launch(void* const* d_in, const int* in_sizes, int n_in,
                              void* d_out, int out_size, void* d_ws, size_t ws_size,
                              hipStream_t stream)
{
  const float* hidden = (const float*)d_in[0];
  const float* rw     = (const float*)d_in[1];
  const float* mk     = (const float*)d_in[2];
  const float* gw1    = (const float*)d_in[3];
  const float* gb1    = (const float*)d_in[4];
  const float* gw2    = (const float*)d_in[5];
  const float* gb2    = (const float*)d_in[6];
  float* out = (float*)d_out;

  unsigned char* ws = (unsigned char*)d_ws;
  size_t o = 0;
  float* mw  = (float*)(ws + o); o += (size_t)EEXP*HDIM*4;    // 1.05 MB
  float* Btr = (float*)(ws + o); o += (size_t)HDIM*H2*4;      // 33.55 MB
  float* h   = (float*)(ws + o); o += (size_t)BROWS*H2*4;     // 134.2 MB
  float* rl  = (float*)(ws + o); o += (size_t)BROWS*EEXP*4;   // 4.19 MB
  float* zb  = (float*)(ws + o); o += (size_t)BROWS*EEXP*4;   // 4.19 MB
  float* s32 = (float*)(ws + o); o += (size_t)BROWS*EEXP*4;   // 4.19 MB
  float* loadp = (float*)(ws + o); o += 64*64*4;
  float* entp  = (float*)(ws + o); o += 256;                  // ~182 MB total

  k_mw32<<<(EEXP*HDIM+255)/256, 256, 0, stream>>>(rw, mk, mw, EEXP*HDIM);
  // Btr[4096][2048] = gw1^T
  k_tr<<<(HDIM/32)*(H2/32), 256, 0, stream>>>(gw1, Btr, H2, HDIM);
  // h = relu(x @ w1^T + b1)
  k_h<<<(BROWS/256)*(H2/128), 256, 0, stream>>>(hidden, Btr, gb1, h);
  // rl = x @ mw^T
  k_g32<<<(BROWS/64)*1, 256, 0, stream>>>(hidden, mw, rl, HDIM, 1, nullptr, 0);
  // z = h @ w2^T
  k_g32<<<(BROWS/64)*1, 256, 0, stream>>>(h, gw2, zb, H2, 1, nullptr, 0);
  k_sig<<<(BROWS*EEXP+255)/256, 256, 0, stream>>>(zb, rl, gb2, s32, out, BROWS*EEXP);
  k_top<<<BROWS/256, 256, 0, stream>>>(s32, out, loadp, entp);
  k_finalize<<<1, 64, 0, stream>>>(loadp, entp, out);
}